// Round 7
// baseline (735.527 us; speedup 1.0000x reference)
//
#include <hip/hip_runtime.h>
#include <hip/hip_bf16.h>

#define H 8
#define C 16
#define HC 128          // H*C
#define NEG 0.2f
#define SCAN_B 256
#define XS_S 132        // LDS row stride (floats) for k1 x-tile

__device__ __forceinline__ float lrelu(float x) { return x > 0.f ? x : NEG * x; }

__device__ __forceinline__ unsigned pack_bf16(float a, float b) {
    union { __hip_bfloat16 h; unsigned short u; } ua, ub;
    ua.h = __float2bfloat16(a);
    ub.h = __float2bfloat16(b);
    return (unsigned)ua.u | ((unsigned)ub.u << 16);
}
__device__ __forceinline__ float bf_lo(unsigned d) { return __uint_as_float(d << 16); }
__device__ __forceinline__ float bf_hi(unsigned d) { return __uint_as_float(d & 0xffff0000u); }

// K1: h = x @ W, fp32 register-tiled GEMM, bf16-packed output.
// Block 256 threads -> 64(rows) x 128(cols) tile. x tile in LDS (33 KB,
// 4 blocks/CU); W streamed through L1 (same 512 B row hit by all waves).
__global__ void __launch_bounds__(256) k1_gemm(const float* __restrict__ x,
                                               const float* __restrict__ W,
                                               unsigned* __restrict__ h16, int N) {
    __shared__ float xs[64 * XS_S];
    const int n0 = blockIdx.x * 64;
    const int t = threadIdx.x;
#pragma unroll
    for (int i = 0; i < 8; ++i) {
        int id = t + 256 * i;           // 2048 float4-chunks
        int r = id >> 5, kq = id & 31;
        int n = n0 + r;
        float4 v = (n < N) ? ((const float4*)x)[(size_t)n * 32 + kq]
                           : make_float4(0.f, 0.f, 0.f, 0.f);
        *(float4*)&xs[r * XS_S + kq * 4] = v;
    }
    __syncthreads();
    const int cg = t & 31;        // cols cg*4..+3
    const int r0 = (t >> 5) * 8;  // rows r0..r0+7
    float acc[8][4];
#pragma unroll
    for (int i = 0; i < 8; ++i)
#pragma unroll
        for (int j = 0; j < 4; ++j) acc[i][j] = 0.f;

#pragma unroll 4
    for (int k = 0; k < HC; ++k) {
        const float4 wv = ((const float4*)W)[k * 32 + cg];
        float wr[4] = {wv.x, wv.y, wv.z, wv.w};
#pragma unroll
        for (int i = 0; i < 8; ++i) {
            float xv = xs[(r0 + i) * XS_S + k];   // broadcast across cg lanes
#pragma unroll
            for (int j = 0; j < 4; ++j) acc[i][j] += xv * wr[j];
        }
    }
#pragma unroll
    for (int i = 0; i < 8; ++i) {
        int n = n0 + r0 + i;
        if (n < N) {
            uint2 dv = make_uint2(pack_bf16(acc[i][0], acc[i][1]),
                                  pack_bf16(acc[i][2], acc[i][3]));
            *(uint2*)&h16[(size_t)n * 64 + cg * 2] = dv;
        }
    }
}

// K_ATT: per-(node,head) attention logits from bf16 h.
__global__ void k_att(const unsigned* __restrict__ h16,
                      const float* __restrict__ att_src,
                      const float* __restrict__ att_dst,
                      float* __restrict__ a_src,
                      float* __restrict__ a_dst, int NH) {
    int idx = blockIdx.x * blockDim.x + threadIdx.x;
    if (idx >= NH) return;
    int n = idx >> 3, hd = idx & 7;
    float s = 0.f, d = 0.f;
#pragma unroll
    for (int c2 = 0; c2 < 8; ++c2) {
        unsigned dv = h16[(size_t)n * 64 + hd * 8 + c2];
        float h0 = bf_lo(dv), h1 = bf_hi(dv);
        s += h0 * att_src[hd * C + 2 * c2] + h1 * att_src[hd * C + 2 * c2 + 1];
        d += h0 * att_dst[hd * C + 2 * c2] + h1 * att_dst[hd * C + 2 * c2 + 1];
    }
    a_src[idx] = s;
    a_dst[idx] = d;
}

// ---- CSR build (by destination) ----

__global__ void kc_count(const int* __restrict__ ei, int* __restrict__ deg, int E) {
    int i = blockIdx.x * blockDim.x + threadIdx.x;
    int E4 = E >> 2;
    if (i < E4) {
        int4 d4 = ((const int4*)(ei + E))[i];
        atomicAdd(&deg[d4.x], 1);
        atomicAdd(&deg[d4.y], 1);
        atomicAdd(&deg[d4.z], 1);
        atomicAdd(&deg[d4.w], 1);
    }
    if (i < (E & 3)) atomicAdd(&deg[ei[E + (E4 << 2) + i]], 1);
}

__global__ void ks_chunk(const int* __restrict__ deg, int* __restrict__ incl,
                         int* __restrict__ bsum, int N) {
    __shared__ int s[SCAN_B];
    int g = blockIdx.x * SCAN_B + threadIdx.x;
    s[threadIdx.x] = (g < N) ? deg[g] : 0;
    __syncthreads();
    for (int off = 1; off < SCAN_B; off <<= 1) {
        int v = (threadIdx.x >= off) ? s[threadIdx.x - off] : 0;
        __syncthreads();
        s[threadIdx.x] += v;
        __syncthreads();
    }
    if (g < N) incl[g] = s[threadIdx.x];
    if (threadIdx.x == SCAN_B - 1) bsum[blockIdx.x] = s[SCAN_B - 1];
}

__global__ void ks_bsum(int* __restrict__ bsum, int nb) {
    __shared__ int s[512];
    int t = threadIdx.x;
    s[t] = (t < nb) ? bsum[t] : 0;
    __syncthreads();
    for (int off = 1; off < 512; off <<= 1) {
        int v = (t >= off) ? s[t - off] : 0;
        __syncthreads();
        s[t] += v;
        __syncthreads();
    }
    if (t < nb) bsum[t] = s[t];
}

__global__ void ks_rowptr(const int* __restrict__ incl, const int* __restrict__ bsum,
                          const int* __restrict__ deg,
                          int* __restrict__ rowptr, int* __restrict__ cursor, int N) {
    int g = blockIdx.x * SCAN_B + threadIdx.x;
    if (g == 0) rowptr[0] = 0;
    if (g < N) {
        int off = (blockIdx.x == 0) ? 0 : bsum[blockIdx.x - 1];
        int inc = incl[g] + off;
        rowptr[g + 1] = inc;
        cursor[g] = inc - deg[g];
    }
}

// KC_SCATTER: place src into its CSR slot. Minimal traffic: ei read (coalesced)
// + cursor atomic (L2-resident) + one 4B scattered col write.
__global__ void kc_scatter(const int* __restrict__ ei,
                           int* __restrict__ cursor, int* __restrict__ col, int E) {
    int e = blockIdx.x * blockDim.x + threadIdx.x;
    if (e >= E) return;
    int dst = ei[E + e], src = ei[e];
    int pos = atomicAdd(&cursor[dst], 1);
    col[pos] = src;
}

// K_PULL: one wave per node, lane t owns channels {2t,2t+1}, head t>>3.
// Per-edge weight computed in-kernel from a_src gather (3.2 MB, L2-resident)
// + wave-resident a_dst: w = exp(lrelu(a_src[src]+a_dst[node])). fp32 weights.
// Pure gather+FMA, 4 independent accumulator sets for MLP.
__global__ void __launch_bounds__(256) k_pull(const int* __restrict__ rowptr,
                                              const int* __restrict__ col,
                                              const unsigned* __restrict__ h16,
                                              const float* __restrict__ a_src,
                                              const float* __restrict__ a_dst,
                                              const float* __restrict__ bias,
                                              float* __restrict__ out, int N) {
    const int node = blockIdx.x * 4 + (threadIdx.x >> 6);
    if (node >= N) return;
    const int t = threadIdx.x & 63;
    const int hd = t >> 3;
    const float ad = a_dst[node * H + hd];
    const float wself = __expf(lrelu(a_src[node * H + hd] + ad));
    unsigned dself = h16[(size_t)node * 64 + t];
    float a0 = bf_lo(dself) * wself, a1 = bf_hi(dself) * wself;
    float b0 = 0.f, b1 = 0.f, c0 = 0.f, c1 = 0.f, e0 = 0.f, e1 = 0.f;
    float sA = wself, sB = 0.f, sC = 0.f, sD = 0.f;

    const int beg = rowptr[node], end = rowptr[node + 1];
    int j = beg;
    for (; j + 4 <= end; j += 4) {
        int nA = col[j], nB = col[j + 1], nC = col[j + 2], nD = col[j + 3];
        float wA = __expf(lrelu(a_src[nA * H + hd] + ad));
        float wB = __expf(lrelu(a_src[nB * H + hd] + ad));
        float wC = __expf(lrelu(a_src[nC * H + hd] + ad));
        float wD = __expf(lrelu(a_src[nD * H + hd] + ad));
        unsigned dA = h16[(size_t)nA * 64 + t];
        unsigned dB = h16[(size_t)nB * 64 + t];
        unsigned dC = h16[(size_t)nC * 64 + t];
        unsigned dD = h16[(size_t)nD * 64 + t];
        a0 += bf_lo(dA) * wA; a1 += bf_hi(dA) * wA; sA += wA;
        b0 += bf_lo(dB) * wB; b1 += bf_hi(dB) * wB; sB += wB;
        c0 += bf_lo(dC) * wC; c1 += bf_hi(dC) * wC; sC += wC;
        e0 += bf_lo(dD) * wD; e1 += bf_hi(dD) * wD; sD += wD;
    }
    for (; j < end; ++j) {
        int nA = col[j];
        float wA = __expf(lrelu(a_src[nA * H + hd] + ad));
        unsigned dA = h16[(size_t)nA * 64 + t];
        a0 += bf_lo(dA) * wA; a1 += bf_hi(dA) * wA; sA += wA;
    }
    const float s = sA + sB + sC + sD;
    const float inv = 1.f / (s + 1e-16f);
    const float acc0 = a0 + b0 + c0 + e0;
    const float acc1 = a1 + b1 + c1 + e1;
    const float2 bv = ((const float2*)bias)[t];
    float2 o;
    o.x = acc0 * inv + bv.x;
    o.y = acc1 * inv + bv.y;
    ((float2*)out)[(size_t)node * 64 + t] = o;
}

extern "C" void kernel_launch(void* const* d_in, const int* in_sizes, int n_in,
                              void* d_out, int out_size, void* d_ws, size_t ws_size,
                              hipStream_t stream) {
    const float* x       = (const float*)d_in[0];
    const int*   ei      = (const int*)d_in[1];
    const float* W       = (const float*)d_in[2];
    const float* att_src = (const float*)d_in[3];
    const float* att_dst = (const float*)d_in[4];
    const float* bias    = (const float*)d_in[5];
    float* out = (float*)d_out;

    const int N = in_sizes[0] / HC;
    const int E = in_sizes[1] / 2;
    const int nb = (N + SCAN_B - 1) / SCAN_B;   // <=512 required for ks_bsum

    // ws: h16[N*64]u32 | a_src[N*8]f | a_dst[N*8]f | deg[N] | incl[N] |
    //     bsum[nb] | rowptr[N+1] | cursor[N] | col[E]   (~47 MB)
    unsigned* h16 = (unsigned*)d_ws;
    float* a_src  = (float*)(h16 + (size_t)N * 64);
    float* a_dst  = a_src + (size_t)N * H;
    int* deg      = (int*)(a_dst + (size_t)N * H);
    int* incl     = deg + N;
    int* bsum     = incl + N;
    int* rowptr   = bsum + nb;
    int* cursor   = rowptr + (N + 1);
    int* col      = cursor + N;

    (void)hipMemsetAsync(deg, 0, (size_t)N * sizeof(int), stream);

    k1_gemm<<<(N + 63) / 64, 256, 0, stream>>>(x, W, h16, N);

    kc_count<<<(E / 4 + 255) / 256, 256, 0, stream>>>(ei, deg, E);
    ks_chunk<<<nb, SCAN_B, 0, stream>>>(deg, incl, bsum, N);
    ks_bsum<<<1, 512, 0, stream>>>(bsum, nb);
    ks_rowptr<<<nb, SCAN_B, 0, stream>>>(incl, bsum, deg, rowptr, cursor, N);

    k_att<<<(N * H + 255) / 256, 256, 0, stream>>>(h16, att_src, att_dst,
                                                   a_src, a_dst, N * H);

    kc_scatter<<<(E + 255) / 256, 256, 0, stream>>>(ei, cursor, col, E);

    k_pull<<<(N + 3) / 4, 256, 0, stream>>>(rowptr, col, h16, a_src,
                                            a_dst, bias, out, N);
}